// Round 12
// baseline (334.451 us; speedup 1.0000x reference)
//
#include <hip/hip_runtime.h>

// PatchDecoder round 12: zero activation-LDS via k-permuted weights.
// Each wave owns 32 q x ALL 128 j; net/h live in registers end-to-end.
// The MFMA D-layout (lane: net[q=lr][j=16jt+4lg+r]) is turned into the next
// layer's B-operand by baking the k-permutation
//   sigma(32kc+8lg+e) = 32kc + 16(e>>2) + 4lg + (e&3)
// into W0/W1's stored A-fragments (convert_weights). Then
//   xf[kc] = [pk4(relu(acc[2kc])), pk4(relu(acc[2kc+1]))]
// is exactly the B-frag for slice kc. No NET/H buffers, no shuffles.
// Schedule: 2 barriers/iter. LDS = lat 10KB + W0 slot 32KB + W1 slot 32KB
// = 74KB -> 2 blocks/CU. W frag reads are frag-linear (16B/lane, conflict-0).
//   PhaseA(i): [stage W1(i) if i>0] fc_c(i) + fc0(i) (reads W0 slot)  | bar_a
//   PhaseB(i): [stage W0(i+1)]      fc1(i)          (reads W1 slot)  | bar_b
// Stages write a slot whose readers retired at the previous barrier and are
// consumed only after the next barrier (global_load_lds drains at barriers).

#define TQ 128
#define BLOCK 256
#define HD 128
#define ZD 32
#define NBLK 5
#define GR 64

typedef _Float16 f16x8 __attribute__((ext_vector_type(8)));
typedef float f32x4 __attribute__((ext_vector_type(4)));

// d_ws layout in halves
#define OFF_P 0            // fc_p_w [128][32] linear (frag-readable)  (4096)
#define OFF_C 4096         // fc_c_w [5][128][32] linear               (20480)
#define OFF_0 24576        // fc0_w  [5][kc4][jt8][l64][e8] sigma      (81920)
#define OFF_1 106496       // fc1_w  [5][kc4][jt8][l64][e8] sigma      (81920)
#define WS_HALVES 188416

__global__ void convert_weights(const float* __restrict__ fc_p_w,
                                const float* __restrict__ fc_c_w,
                                const float* __restrict__ fc0_w,
                                const float* __restrict__ fc1_w,
                                _Float16* __restrict__ ws) {
  int i = blockIdx.x * 256 + threadIdx.x;
  if (i >= WS_HALVES) return;
  if (i < 4096) {  // Wp linear (lane reads (16jt+lr)*32 + 8lg, contiguous 8)
    ws[OFF_P + i] = (_Float16)fc_p_w[i];
    return;
  }
  i -= 4096;
  if (i < 20480) {  // Wc linear
    ws[OFF_C + i] = (_Float16)fc_c_w[i];
    return;
  }
  i -= 20480;
  if (i < 81920) {  // W0 sigma frag-linear: [li][kc][jt][l][e]
    const int li = i >> 14, idx = i & 16383;
    const int e = idx & 7, l = (idx >> 3) & 63;
    const int jt = (idx >> 9) & 7, kc = (idx >> 12) & 3;
    const int row = 16 * jt + (l & 15);
    const int col = 32 * kc + 16 * (e >> 2) + 4 * (l >> 4) + (e & 3);
    ws[OFF_0 + i] = (_Float16)fc0_w[li * 16384 + row * 128 + col];
    return;
  }
  i -= 81920;
  {  // W1 sigma frag-linear: [li][kc][jt][l][e]
    const int li = i >> 14, idx = i & 16383;
    const int e = idx & 7, l = (idx >> 3) & 63;
    const int jt = (idx >> 9) & 7, kc = (idx >> 12) & 3;
    const int row = 16 * jt + (l & 15);
    const int col = 32 * kc + 16 * (e >> 2) + 4 * (l >> 4) + (e & 3);
    ws[OFF_1 + i] = (_Float16)fc1_w[li * 16384 + row * 128 + col];
  }
}

struct SMem {
  _Float16 lat[TQ * 40];    // 10240 B gather latents, 80B rows; NEVER rewritten
  _Float16 W0s[16384];      // 32KB W0 layer slot, sigma frag-linear
  _Float16 W1s[16384];      // 32KB W1 layer slot
};

// stage one 32KB layer chunk: 256 thr x 16B x 8, LDS-linear
__device__ __forceinline__ void stage32(char* lds, const char* g, int t) {
#pragma unroll
  for (int r = 0; r < 8; ++r) {
    __builtin_amdgcn_global_load_lds(
        (const __attribute__((address_space(1))) void*)(g + r * 4096 + t * 16),
        (__attribute__((address_space(3))) void*)(lds + r * 4096 + t * 16), 16,
        0, 0);
  }
}

// relu + pack two f32x4 (8 consecutive acc values) into one B-frag
__device__ __forceinline__ f16x8 pack_relu8(const f32x4 a, const f32x4 b) {
  f16x8 r;
#pragma unroll
  for (int i = 0; i < 4; ++i) r[i] = (_Float16)fmaxf(a[i], 0.f);
#pragma unroll
  for (int i = 0; i < 4; ++i) r[4 + i] = (_Float16)fmaxf(b[i], 0.f);
  return r;
}

__global__ __launch_bounds__(BLOCK, 2) void patch_decoder_kernel(
    const float* __restrict__ z_feats, const float* __restrict__ query,
    const _Float16* __restrict__ ws, const float* __restrict__ fc_p_b,
    const float* __restrict__ fc_c_b, const float* __restrict__ fc0_b,
    const float* __restrict__ fc1_b, const float* __restrict__ fc_out_w,
    const float* __restrict__ fc_out_b, float* __restrict__ out, int nq) {
  __shared__ SMem sm;
  const int t = threadIdx.x;
  const int w = t >> 6;
  const int l = t & 63;
  const int lr = l & 15, lg = l >> 4;
  const int qe = w << 5;  // wave's 32-query slice
  const int qbase = blockIdx.x * TQ;

  const char* w0base = (const char*)(ws + OFF_0);
  const char* w1base = (const char*)(ws + OFF_1);

  // ---- prologue: stage layer-0 W0+W1 (lands during gather) ----
  stage32((char*)sm.W0s, w0base, t);
  stage32((char*)sm.W1s, w1base, t);

  // ---- gather: 2 threads/query, 16 feats each; -> lat (80B rows) ----
  {
    const int q = t >> 1, s = t & 1;
    const int qg = qbase + q;
    float acc[16];
#pragma unroll
    for (int e = 0; e < 16; ++e) acc[e] = 0.f;
    if (qg < nq) {
      const float qx = query[qg * 3 + 0];
      const float qy = query[qg * 3 + 1];
      const float qz = query[qg * 3 + 2];
      const float fx = floorf(qx), fy = floorf(qy), fz = floorf(qz);
      const float rx = qx - fx, ry = qy - fy, rz = qz - fz;
      const int bx = (int)fx, by = (int)fy, bz = (int)fz;
      const float wx[2] = {1.f - rx, rx}, wy[2] = {1.f - ry, ry},
                  wz[2] = {1.f - rz, rz};
#pragma unroll
      for (int c = 0; c < 8; ++c) {
        const int ox = (c >> 2) & 1, oy = (c >> 1) & 1, oz = c & 1;
        const float wgt = wx[ox] * wy[oy] * wz[oz];
        const float* f = z_feats +
                         (size_t)(((bx + ox) * GR + (by + oy)) * GR + (bz + oz)) * ZD +
                         s * 16;
#pragma unroll
        for (int v4 = 0; v4 < 4; ++v4) {
          const float4 v = *(const float4*)(f + v4 * 4);
          acc[v4 * 4 + 0] = fmaf(wgt, v.x, acc[v4 * 4 + 0]);
          acc[v4 * 4 + 1] = fmaf(wgt, v.y, acc[v4 * 4 + 1]);
          acc[v4 * 4 + 2] = fmaf(wgt, v.z, acc[v4 * 4 + 2]);
          acc[v4 * 4 + 3] = fmaf(wgt, v.w, acc[v4 * 4 + 3]);
        }
      }
    }
    f16x8 h0, h1;
#pragma unroll
    for (int e = 0; e < 8; ++e) {
      h0[e] = (_Float16)acc[e];
      h1[e] = (_Float16)acc[8 + e];
    }
    char* lb = (char*)sm.lat + q * 80 + s * 32;
    *(f16x8*)lb = h0;
    *(f16x8*)(lb + 16) = h1;
  }
  __syncthreads();  // bar0: lat visible; layer-0 W slots drained

  // ---- latf (persist; lat buffer is never rewritten -> race-free) ----
  f16x8 latf[2];
#pragma unroll
  for (int qt = 0; qt < 2; ++qt)
    latf[qt] =
        *(const f16x8*)((const char*)sm.lat + (qe + 16 * qt + lr) * 80 + lg * 16);

  // ---- fc_p: acc[jt][qt] = bias + Wp x lat ----
  f32x4 acc[8][2];
#pragma unroll
  for (int jt = 0; jt < 8; ++jt) {
    const f32x4 bv = *(const f32x4*)(fc_p_b + 16 * jt + 4 * lg);
    acc[jt][0] = bv;
    acc[jt][1] = bv;
  }
#pragma unroll
  for (int jt = 0; jt < 8; ++jt) {
    const f16x8 wf = *(const f16x8*)(ws + OFF_P + (16 * jt + lr) * 32 + lg * 8);
#pragma unroll
    for (int qt = 0; qt < 2; ++qt)
      acc[jt][qt] = __builtin_amdgcn_mfma_f32_16x16x32_f16(wf, latf[qt], acc[jt][qt],
                                                           0, 0, 0);
  }

#pragma unroll 1
  for (int i = 0; i < NBLK; ++i) {
    // ======== Phase A: fc_c + fc0 (reads W0 slot) ========
    if (i > 0) stage32((char*)sm.W1s, w1base + i * 32768, t);  // W1(i)
    // fc_c: acc += Wc x lat + bias
#pragma unroll
    for (int jt = 0; jt < 8; ++jt) {
      const f16x8 wf =
          *(const f16x8*)(ws + OFF_C + i * 4096 + (16 * jt + lr) * 32 + lg * 8);
      __builtin_amdgcn_s_setprio(1);
#pragma unroll
      for (int qt = 0; qt < 2; ++qt)
        acc[jt][qt] = __builtin_amdgcn_mfma_f32_16x16x32_f16(wf, latf[qt],
                                                             acc[jt][qt], 0, 0, 0);
      __builtin_amdgcn_s_setprio(0);
      const f32x4 bv = *(const f32x4*)(fc_c_b + i * HD + 16 * jt + 4 * lg);
      acc[jt][0] += bv;
      acc[jt][1] += bv;
    }
    // fc0: hacc = b0 + W0 x relu(net);  B-frags straight from acc (sigma)
    f32x4 hacc[8][2];
#pragma unroll
    for (int jt = 0; jt < 8; ++jt) {
      const f32x4 bv = *(const f32x4*)(fc0_b + i * HD + 16 * jt + 4 * lg);
      hacc[jt][0] = bv;
      hacc[jt][1] = bv;
    }
#pragma unroll
    for (int kc = 0; kc < 4; ++kc) {
      f16x8 xf[2];
#pragma unroll
      for (int qt = 0; qt < 2; ++qt)
        xf[qt] = pack_relu8(acc[2 * kc][qt], acc[2 * kc + 1][qt]);
#pragma unroll
      for (int jt = 0; jt < 8; ++jt) {
        const f16x8 af =
            *(const f16x8*)((const char*)sm.W0s + ((kc * 8 + jt) * 64 + l) * 16);
        __builtin_amdgcn_s_setprio(1);
#pragma unroll
        for (int qt = 0; qt < 2; ++qt)
          hacc[jt][qt] = __builtin_amdgcn_mfma_f32_16x16x32_f16(af, xf[qt],
                                                                hacc[jt][qt], 0, 0, 0);
        __builtin_amdgcn_s_setprio(0);
      }
    }
    __syncthreads();  // bar_a: W0 readers retired; W1(i) staged+drained

    // ======== Phase B: fc1 (reads W1 slot) ========
    if (i + 1 < NBLK) stage32((char*)sm.W0s, w0base + (i + 1) * 32768, t);
#pragma unroll
    for (int kc = 0; kc < 4; ++kc) {
      f16x8 hf[2];
#pragma unroll
      for (int qt = 0; qt < 2; ++qt)
        hf[qt] = pack_relu8(hacc[2 * kc][qt], hacc[2 * kc + 1][qt]);
#pragma unroll
      for (int jt = 0; jt < 8; ++jt) {
        const f16x8 a1 =
            *(const f16x8*)((const char*)sm.W1s + ((kc * 8 + jt) * 64 + l) * 16);
        __builtin_amdgcn_s_setprio(1);
#pragma unroll
        for (int qt = 0; qt < 2; ++qt)
          acc[jt][qt] = __builtin_amdgcn_mfma_f32_16x16x32_f16(a1, hf[qt],
                                                               acc[jt][qt], 0, 0, 0);
        __builtin_amdgcn_s_setprio(0);
      }
    }
#pragma unroll
    for (int jt = 0; jt < 8; ++jt) {
      const f32x4 bv = *(const f32x4*)(fc1_b + i * HD + 16 * jt + 4 * lg);
      acc[jt][0] += bv;
      acc[jt][1] += bv;
    }
    __syncthreads();  // bar_b: W1 readers retired; W0(i+1) staged+drained
  }

  // ---- epilogue (registers only): out[q] = leaky(net).wout + b ----
  {
    const float ob = fc_out_b[0];
#pragma unroll
    for (int qt = 0; qt < 2; ++qt) {
      float p = 0.f;
#pragma unroll
      for (int jt = 0; jt < 8; ++jt) {
        const f32x4 wv = *(const f32x4*)(fc_out_w + 16 * jt + 4 * lg);
        const f32x4 a = acc[jt][qt];
#pragma unroll
        for (int r = 0; r < 4; ++r) {
          const float v = (a[r] > 0.f) ? a[r] : 0.2f * a[r];
          p = fmaf(v, wv[r], p);
        }
      }
      p += __shfl_xor(p, 16);
      p += __shfl_xor(p, 32);
      const int qg = qbase + qe + 16 * qt + lr;
      if (lg == 0 && qg < nq) out[qg] = p + ob;
    }
  }
}

extern "C" void kernel_launch(void* const* d_in, const int* in_sizes, int n_in,
                              void* d_out, int out_size, void* d_ws,
                              size_t ws_size, hipStream_t stream) {
  const float* z_feats = (const float*)d_in[0];
  const float* query = (const float*)d_in[1];
  const float* fc_p_w = (const float*)d_in[2];
  const float* fc_p_b = (const float*)d_in[3];
  const float* fc_c_w = (const float*)d_in[4];
  const float* fc_c_b = (const float*)d_in[5];
  const float* fc0_w = (const float*)d_in[6];
  const float* fc0_b = (const float*)d_in[7];
  const float* fc1_w = (const float*)d_in[8];
  const float* fc1_b = (const float*)d_in[9];
  const float* fc_out_w = (const float*)d_in[10];
  const float* fc_out_b = (const float*)d_in[11];
  float* out = (float*)d_out;
  _Float16* ws = (_Float16*)d_ws;

  const int nq = in_sizes[1] / 3;

  convert_weights<<<(WS_HALVES + 255) / 256, 256, 0, stream>>>(fc_p_w, fc_c_w,
                                                               fc0_w, fc1_w, ws);
  const int grid = (nq + TQ - 1) / TQ;
  patch_decoder_kernel<<<grid, BLOCK, 0, stream>>>(z_feats, query, ws, fc_p_b,
                                                   fc_c_b, fc0_b, fc1_b, fc_out_w,
                                                   fc_out_b, out, nq);
}